// Round 1
// 97.696 us; speedup vs baseline: 1.1045x; 1.1045x over previous
//
#include <hip/hip_runtime.h>

// Problem constants (B=2, H=8, L=1024, D=64)
#define N_HEADS 16          // B*H
#define L_SEQ   1024
#define D_HEAD  64
#define D2      128         // 2*D (sin/cos concat)
#define T_CHUNK 32
#define N_CHUNK (L_SEQ / T_CHUNK)   // 32
#define KV_ELEMS (D2 * D_HEAD)      // 8192

// Padded LDS row: insert a 4-float gap every 32 columns so the 8 g-groups
// (float4 reads at 16-col offsets) cover all 32 banks conflict-free.
#define ROWP 140
#define PARTP 132

__device__ __forceinline__ int pad_col(int d2) { return d2 + 4 * (d2 >> 5); }

#define SINCOS_SCALE 1.53398078788564122971e-3f   // (pi/2)/1024

// ---------------------------------------------------------------------------
// K1: per-(chunk, head) local sums. 512 threads, 8-way d2 split (16 d2/thread).
//   sumkv flat layout (thread-interleaved float4): f4_idx = j4*512 + tid
//   sumk[d2] computed ONCE by 128 threads (not redundantly by all).
// ---------------------------------------------------------------------------
__global__ __launch_bounds__(512, 4) void k1_chunk_sums(
    const float* __restrict__ k, const float* __restrict__ v,
    float* __restrict__ sumkv, float* __restrict__ sumk)
{
    __shared__ __attribute__((aligned(16))) float k_s[T_CHUNK][ROWP];
    __shared__ float v_s[T_CHUNK][D_HEAD];
    __shared__ float s_tab[T_CHUNK], c_tab[T_CHUNK];

    const int c = blockIdx.x, n = blockIdx.y;
    const int tid = threadIdx.x;
    const int base = (n * L_SEQ + c * T_CHUNK) * D_HEAD;

    if (tid < T_CHUNK) {
        float th = SINCOS_SCALE * (float)(c * T_CHUNK + tid + 1);
        s_tab[tid] = __sinf(th);
        c_tab[tid] = __cosf(th);
    }
    __syncthreads();

#pragma unroll
    for (int i = tid; i < T_CHUNK * D_HEAD; i += 512) {
        int l = i >> 6, d = i & 63;
        float kr = fmaxf(k[base + i], 0.f);
        float vr = fmaxf(v[base + i], 0.f);
        float s = s_tab[l], cs = c_tab[l];
        k_s[l][pad_col(d)]      = kr * s;
        k_s[l][pad_col(d + 64)] = kr * cs;
        v_s[l][d] = vr;
    }
    __syncthreads();

    // Column sums of k_ -> sumk, computed once (was 64x redundant).
    if (tid < D2) {
        int pc = pad_col(tid);
        float ks = 0.f;
#pragma unroll
        for (int l = 0; l < T_CHUNK; ++l) ks += k_s[l][pc];
        sumk[(n * N_CHUNK + c) * D2 + tid] = ks;
    }

    const int g = tid & 7, m = tid >> 3;
    const int gbase = pad_col(16 * g);

    float st[16];
#pragma unroll
    for (int j = 0; j < 16; ++j) st[j] = 0.f;

    for (int l = 0; l < T_CHUNK; ++l) {
        float vm = v_s[l][m];
        const float4* kv4 = (const float4*)&k_s[l][gbase];
#pragma unroll
        for (int jj = 0; jj < 4; ++jj) {
            float4 kk = kv4[jj];
            st[4*jj+0] = fmaf(kk.x, vm, st[4*jj+0]);
            st[4*jj+1] = fmaf(kk.y, vm, st[4*jj+1]);
            st[4*jj+2] = fmaf(kk.z, vm, st[4*jj+2]);
            st[4*jj+3] = fmaf(kk.w, vm, st[4*jj+3]);
        }
    }

    // Coalesced float4 stores: wave writes 1 KB contiguous per instruction.
    float4* dst = (float4*)(sumkv + (size_t)(n * N_CHUNK + c) * KV_ELEMS);
#pragma unroll
    for (int j4 = 0; j4 < 4; ++j4)
        dst[j4 * 512 + tid] = make_float4(st[4*j4+0], st[4*j4+1], st[4*j4+2], st[4*j4+3]);
}

// ---------------------------------------------------------------------------
// K2: exclusive prefix over chunks. 512 blocks for sumkv (1 elem/thread),
// fully unrolled 32-deep load pipeline (addresses data-independent -> MLP).
// ---------------------------------------------------------------------------
__global__ __launch_bounds__(256) void k2_prefix(
    float* __restrict__ sumkv, float* __restrict__ sumk)
{
    const int x = blockIdx.x, n = blockIdx.y;
    const int tid = threadIdx.x;

    if (x < 32) {
        float* base = sumkv + (size_t)n * N_CHUNK * KV_ELEMS + x * 256 + tid;
        float t[N_CHUNK];
#pragma unroll
        for (int c = 0; c < N_CHUNK; ++c) t[c] = base[c * KV_ELEMS];
        float r = 0.f;
#pragma unroll
        for (int c = 0; c < N_CHUNK; ++c) { base[c * KV_ELEMS] = r; r += t[c]; }
    } else if (tid < D2) {
        float* bk = sumk + n * N_CHUNK * D2 + tid;
        float t[N_CHUNK];
#pragma unroll
        for (int c = 0; c < N_CHUNK; ++c) t[c] = bk[c * D2];
        float r = 0.f;
#pragma unroll
        for (int c = 0; c < N_CHUNK; ++c) { bk[c * D2] = r; r += t[c]; }
    }
}

// ---------------------------------------------------------------------------
// K3: outputs. 512 threads, 8-way d2 split. Denominator (shared across all m)
// precomputed ONCE per block by a 128-thread column scan + tree reduce
// (was computed 16x redundantly = half the inner-loop FLOPs).
// ---------------------------------------------------------------------------
__global__ __launch_bounds__(512, 4) void k3_output(
    const float* __restrict__ q, const float* __restrict__ k,
    const float* __restrict__ v, const float* __restrict__ sumkv,
    const float* __restrict__ sumk, float* __restrict__ out)
{
    __shared__ __attribute__((aligned(16))) float k_s[T_CHUNK][ROWP];
    __shared__ __attribute__((aligned(16))) float q_s[T_CHUNK][ROWP];
    __shared__ float v_s[T_CHUNK][D_HEAD];
    __shared__ float part_s[T_CHUNK][PARTP];
    __shared__ float rden_s[T_CHUNK];
    __shared__ __attribute__((aligned(16))) float out_s[T_CHUNK][D_HEAD];
    __shared__ float s_tab[T_CHUNK], c_tab[T_CHUNK];

    const int c = blockIdx.x, n = blockIdx.y;
    const int tid = threadIdx.x;
    const int base = (n * L_SEQ + c * T_CHUNK) * D_HEAD;

    if (tid < T_CHUNK) {
        float th = SINCOS_SCALE * (float)(c * T_CHUNK + tid + 1);
        s_tab[tid] = __sinf(th);
        c_tab[tid] = __cosf(th);
    }
    __syncthreads();

#pragma unroll
    for (int i = tid; i < T_CHUNK * D_HEAD; i += 512) {
        int l = i >> 6, d = i & 63;
        float kr = fmaxf(k[base + i], 0.f);
        float qr = fmaxf(q[base + i], 0.f);
        float vr = fmaxf(v[base + i], 0.f);
        float s = s_tab[l], cs = c_tab[l];
        k_s[l][pad_col(d)]      = kr * s;
        k_s[l][pad_col(d + 64)] = kr * cs;
        q_s[l][pad_col(d)]      = qr * s;
        q_s[l][pad_col(d + 64)] = qr * cs;
        v_s[l][d] = vr;
    }

    // Issue global loads of prefix state before the barrier (latency overlap).
    const float4* pkv = (const float4*)(sumkv + (size_t)(n * N_CHUNK + c) * KV_ELEMS);
    float4 s0 = pkv[0 * 512 + tid];
    float4 s1 = pkv[1 * 512 + tid];
    float4 s2 = pkv[2 * 512 + tid];
    float4 s3 = pkv[3 * 512 + tid];
    float kc = 0.f;
    if (tid < D2) kc = sumk[(n * N_CHUNK + c) * D2 + tid];

    __syncthreads();

    // Denominator precompute: per-column running k-cumsum * q, once per block.
    if (tid < D2) {
        int pc = pad_col(tid);
#pragma unroll
        for (int l = 0; l < T_CHUNK; ++l) {
            kc += k_s[l][pc];
            part_s[l][tid] = q_s[l][pc] * kc;
        }
    }
    __syncthreads();

    {
        int l = tid >> 4, j = tid & 15;
        float sum = 0.f;
#pragma unroll
        for (int i = 0; i < 8; ++i) sum += part_s[l][j * 8 + i];
        sum += __shfl_xor(sum, 1, 64);
        sum += __shfl_xor(sum, 2, 64);
        sum += __shfl_xor(sum, 4, 64);
        sum += __shfl_xor(sum, 8, 64);
        if (j == 0) rden_s[l] = 1.f / fmaxf(sum, 1e-6f);
    }
    __syncthreads();

    const int g = tid & 7, m = tid >> 3;
    const int gbase = pad_col(16 * g);

    float st[16];
    st[0]=s0.x; st[1]=s0.y; st[2]=s0.z; st[3]=s0.w;
    st[4]=s1.x; st[5]=s1.y; st[6]=s1.z; st[7]=s1.w;
    st[8]=s2.x; st[9]=s2.y; st[10]=s2.z; st[11]=s2.w;
    st[12]=s3.x; st[13]=s3.y; st[14]=s3.z; st[15]=s3.w;

    for (int l = 0; l < T_CHUNK; ++l) {
        float vm = v_s[l][m];
        const float4* kv4 = (const float4*)&k_s[l][gbase];
        const float4* qv4 = (const float4*)&q_s[l][gbase];
        float a0 = 0.f, a1 = 0.f;
#pragma unroll
        for (int jj = 0; jj < 4; ++jj) {
            float4 kk = kv4[jj];
            float4 qq = qv4[jj];
            st[4*jj+0] = fmaf(kk.x, vm, st[4*jj+0]); a0 = fmaf(qq.x, st[4*jj+0], a0);
            st[4*jj+1] = fmaf(kk.y, vm, st[4*jj+1]); a1 = fmaf(qq.y, st[4*jj+1], a1);
            st[4*jj+2] = fmaf(kk.z, vm, st[4*jj+2]); a0 = fmaf(qq.z, st[4*jj+2], a0);
            st[4*jj+3] = fmaf(kk.w, vm, st[4*jj+3]); a1 = fmaf(qq.w, st[4*jj+3], a1);
        }
        float a = a0 + a1;
        a += __shfl_xor(a, 1, 64);
        a += __shfl_xor(a, 2, 64);
        a += __shfl_xor(a, 4, 64);
        if (g == 0) out_s[l][m] = a * rden_s[l];
    }
    __syncthreads();

    // Coalesced output store.
    {
        float4* o4 = (float4*)(out + base);
        const float4* s4 = (const float4*)&out_s[0][0];
        o4[tid] = s4[tid];
    }
}

// ---------------------------------------------------------------------------
extern "C" void kernel_launch(void* const* d_in, const int* in_sizes, int n_in,
                              void* d_out, int out_size, void* d_ws, size_t ws_size,
                              hipStream_t stream) {
    (void)in_sizes; (void)n_in; (void)out_size; (void)ws_size;
    const float* q = (const float*)d_in[0];
    const float* k = (const float*)d_in[1];
    const float* v = (const float*)d_in[2];
    float* out = (float*)d_out;

    float* sumkv = (float*)d_ws;                                   // [N][C][8192] flat
    float* sumk  = sumkv + (size_t)N_HEADS * N_CHUNK * KV_ELEMS;   // [N][C][128]

    dim3 grid(N_CHUNK, N_HEADS);
    k1_chunk_sums<<<grid, 512, 0, stream>>>(k, v, sumkv, sumk);
    dim3 grid2(33, N_HEADS);
    k2_prefix<<<grid2, 256, 0, stream>>>(sumkv, sumk);
    k3_output<<<grid, 512, 0, stream>>>(q, k, v, sumkv, sumk, out);
}

// Round 2
// 90.897 us; speedup vs baseline: 1.1871x; 1.0748x over previous
//
#include <hip/hip_runtime.h>

// Problem constants (B=2, H=8, L=1024, D=64)
#define N_HEADS 16          // B*H
#define L_SEQ   1024
#define D_HEAD  64
#define D2      128         // 2*D (sin/cos concat)
#define T_CHUNK 32
#define N_CHUNK (L_SEQ / T_CHUNK)   // 32
#define KV_ELEMS (D2 * D_HEAD)      // 8192

// Padded LDS row: insert a 4-float gap every 32 columns so the 8 g-groups
// (float4 reads at 16-col offsets) cover all 32 banks conflict-free.
#define ROWP 140
#define PARTP 132

__device__ __forceinline__ int pad_col(int d2) { return d2 + 4 * (d2 >> 5); }

#define SINCOS_SCALE 1.53398078788564122971e-3f   // (pi/2)/1024

// Sum over the 8 lanes differing in bits 0..2, entirely on the VALU (DPP),
// keeping the LDS pipe free for the ds_read_b128 stream.
// xor1 = quad_perm(1,0,3,2)=0xB1, xor2 = quad_perm(2,3,0,1)=0x4E,
// xor{1,2,4 combined} final step = row_half_mirror (0x141, lane ^= 7 within 8).
__device__ __forceinline__ float red8_dpp(float x) {
    x += __int_as_float(__builtin_amdgcn_mov_dpp(__float_as_int(x), 0xB1, 0xF, 0xF, true));
    x += __int_as_float(__builtin_amdgcn_mov_dpp(__float_as_int(x), 0x4E, 0xF, 0xF, true));
    x += __int_as_float(__builtin_amdgcn_mov_dpp(__float_as_int(x), 0x141, 0xF, 0xF, true));
    return x;
}

// ---------------------------------------------------------------------------
// K1: per-(chunk, head) local sums. 256 threads; each thread owns 16 d2 cols
// (g = tid&7) x 2 m cols (mh, mh+1) -> 2 FMA per LDS float read (M=2).
// ---------------------------------------------------------------------------
__global__ __launch_bounds__(256, 2) void k1_chunk_sums(
    const float* __restrict__ k, const float* __restrict__ v,
    float* __restrict__ sumkv, float* __restrict__ sumk)
{
    __shared__ __attribute__((aligned(16))) float k_s[T_CHUNK][ROWP];
    __shared__ __attribute__((aligned(16))) float v_s[T_CHUNK][D_HEAD];
    __shared__ float s_tab[T_CHUNK], c_tab[T_CHUNK];

    const int c = blockIdx.x, n = blockIdx.y;
    const int tid = threadIdx.x;
    const int base = (n * L_SEQ + c * T_CHUNK) * D_HEAD;

    if (tid < T_CHUNK) {
        float th = SINCOS_SCALE * (float)(c * T_CHUNK + tid + 1);
        s_tab[tid] = __sinf(th);
        c_tab[tid] = __cosf(th);
    }
    __syncthreads();

    // Vectorized staging: float4 global loads, float4 LDS stores.
    const float4* k4g = (const float4*)(k + base);
    const float4* v4g = (const float4*)(v + base);
#pragma unroll
    for (int j = 0; j < 2; ++j) {
        int i4 = j * 256 + tid;            // 0..511
        int l = i4 >> 4, d = (i4 & 15) << 2;
        float4 kk = k4g[i4], vv = v4g[i4];
        kk.x = fmaxf(kk.x, 0.f); kk.y = fmaxf(kk.y, 0.f);
        kk.z = fmaxf(kk.z, 0.f); kk.w = fmaxf(kk.w, 0.f);
        vv.x = fmaxf(vv.x, 0.f); vv.y = fmaxf(vv.y, 0.f);
        vv.z = fmaxf(vv.z, 0.f); vv.w = fmaxf(vv.w, 0.f);
        float s = s_tab[l], cs = c_tab[l];
        *(float4*)&k_s[l][pad_col(d)]      = make_float4(kk.x*s,  kk.y*s,  kk.z*s,  kk.w*s);
        *(float4*)&k_s[l][pad_col(d + 64)] = make_float4(kk.x*cs, kk.y*cs, kk.z*cs, kk.w*cs);
        *(float4*)&v_s[l][d] = vv;
    }
    __syncthreads();

    // Column sums of k_ -> sumk, computed once.
    if (tid < D2) {
        int pc = pad_col(tid);
        float ks = 0.f;
#pragma unroll
        for (int l = 0; l < T_CHUNK; ++l) ks += k_s[l][pc];
        sumk[(n * N_CHUNK + c) * D2 + tid] = ks;
    }

    const int g = tid & 7, mh = (tid >> 3) << 1;
    const int gbase = pad_col(16 * g);

    float st0[16], st1[16];
#pragma unroll
    for (int j = 0; j < 16; ++j) { st0[j] = 0.f; st1[j] = 0.f; }

    for (int l = 0; l < T_CHUNK; ++l) {
        float2 vm = *(const float2*)&v_s[l][mh];
        const float4* kv4 = (const float4*)&k_s[l][gbase];
#pragma unroll
        for (int jj = 0; jj < 4; ++jj) {
            float4 kk = kv4[jj];
            st0[4*jj+0] = fmaf(kk.x, vm.x, st0[4*jj+0]);
            st1[4*jj+0] = fmaf(kk.x, vm.y, st1[4*jj+0]);
            st0[4*jj+1] = fmaf(kk.y, vm.x, st0[4*jj+1]);
            st1[4*jj+1] = fmaf(kk.y, vm.y, st1[4*jj+1]);
            st0[4*jj+2] = fmaf(kk.z, vm.x, st0[4*jj+2]);
            st1[4*jj+2] = fmaf(kk.z, vm.y, st1[4*jj+2]);
            st0[4*jj+3] = fmaf(kk.w, vm.x, st0[4*jj+3]);
            st1[4*jj+3] = fmaf(kk.w, vm.y, st1[4*jj+3]);
        }
    }

    // Coalesced float4 stores, thread-interleaved flat layout (K3 mirrors it).
    float4* dst = (float4*)(sumkv + (size_t)(n * N_CHUNK + c) * KV_ELEMS);
#pragma unroll
    for (int j4 = 0; j4 < 4; ++j4) {
        dst[(2*j4+0)*256 + tid] = make_float4(st0[4*j4], st0[4*j4+1], st0[4*j4+2], st0[4*j4+3]);
        dst[(2*j4+1)*256 + tid] = make_float4(st1[4*j4], st1[4*j4+1], st1[4*j4+2], st1[4*j4+3]);
    }
}

// ---------------------------------------------------------------------------
// K2: exclusive prefix over chunks, 1 elem/thread, fully unrolled 32-deep
// load pipeline (data-independent addresses -> memory-level parallelism).
// ---------------------------------------------------------------------------
__global__ __launch_bounds__(256) void k2_prefix(
    float* __restrict__ sumkv, float* __restrict__ sumk)
{
    const int x = blockIdx.x, n = blockIdx.y;
    const int tid = threadIdx.x;

    if (x < 32) {
        float* base = sumkv + (size_t)n * N_CHUNK * KV_ELEMS + x * 256 + tid;
        float t[N_CHUNK];
#pragma unroll
        for (int c = 0; c < N_CHUNK; ++c) t[c] = base[c * KV_ELEMS];
        float r = 0.f;
#pragma unroll
        for (int c = 0; c < N_CHUNK; ++c) { base[c * KV_ELEMS] = r; r += t[c]; }
    } else if (tid < D2) {
        float* bk = sumk + n * N_CHUNK * D2 + tid;
        float t[N_CHUNK];
#pragma unroll
        for (int c = 0; c < N_CHUNK; ++c) t[c] = bk[c * D2];
        float r = 0.f;
#pragma unroll
        for (int c = 0; c < N_CHUNK; ++c) { bk[c * D2] = r; r += t[c]; }
    }
}

// ---------------------------------------------------------------------------
// K3: outputs. 256 threads, M=2 (two m-cols/thread), DPP reductions,
// denominator precomputed once per block by a 128-thread column scan.
// ---------------------------------------------------------------------------
__global__ __launch_bounds__(256, 2) void k3_output(
    const float* __restrict__ q, const float* __restrict__ k,
    const float* __restrict__ v, const float* __restrict__ sumkv,
    const float* __restrict__ sumk, float* __restrict__ out)
{
    __shared__ __attribute__((aligned(16))) float k_s[T_CHUNK][ROWP];
    __shared__ __attribute__((aligned(16))) float q_s[T_CHUNK][ROWP];
    __shared__ __attribute__((aligned(16))) float v_s[T_CHUNK][D_HEAD];
    __shared__ __attribute__((aligned(16))) float part_s[T_CHUNK][PARTP];
    __shared__ float rden_s[T_CHUNK];
    __shared__ __attribute__((aligned(16))) float out_s[T_CHUNK][D_HEAD];
    __shared__ float s_tab[T_CHUNK], c_tab[T_CHUNK];

    const int c = blockIdx.x, n = blockIdx.y;
    const int tid = threadIdx.x;
    const int base = (n * L_SEQ + c * T_CHUNK) * D_HEAD;

    if (tid < T_CHUNK) {
        float th = SINCOS_SCALE * (float)(c * T_CHUNK + tid + 1);
        s_tab[tid] = __sinf(th);
        c_tab[tid] = __cosf(th);
    }
    __syncthreads();

    const float4* q4g = (const float4*)(q + base);
    const float4* k4g = (const float4*)(k + base);
    const float4* v4g = (const float4*)(v + base);
#pragma unroll
    for (int j = 0; j < 2; ++j) {
        int i4 = j * 256 + tid;
        int l = i4 >> 4, d = (i4 & 15) << 2;
        float4 kk = k4g[i4], qq = q4g[i4], vv = v4g[i4];
        kk.x = fmaxf(kk.x, 0.f); kk.y = fmaxf(kk.y, 0.f);
        kk.z = fmaxf(kk.z, 0.f); kk.w = fmaxf(kk.w, 0.f);
        qq.x = fmaxf(qq.x, 0.f); qq.y = fmaxf(qq.y, 0.f);
        qq.z = fmaxf(qq.z, 0.f); qq.w = fmaxf(qq.w, 0.f);
        vv.x = fmaxf(vv.x, 0.f); vv.y = fmaxf(vv.y, 0.f);
        vv.z = fmaxf(vv.z, 0.f); vv.w = fmaxf(vv.w, 0.f);
        float s = s_tab[l], cs = c_tab[l];
        *(float4*)&k_s[l][pad_col(d)]      = make_float4(kk.x*s,  kk.y*s,  kk.z*s,  kk.w*s);
        *(float4*)&k_s[l][pad_col(d + 64)] = make_float4(kk.x*cs, kk.y*cs, kk.z*cs, kk.w*cs);
        *(float4*)&q_s[l][pad_col(d)]      = make_float4(qq.x*s,  qq.y*s,  qq.z*s,  qq.w*s);
        *(float4*)&q_s[l][pad_col(d + 64)] = make_float4(qq.x*cs, qq.y*cs, qq.z*cs, qq.w*cs);
        *(float4*)&v_s[l][d] = vv;
    }

    // Issue global loads of prefix state before the barrier (latency overlap).
    const float4* pkv = (const float4*)(sumkv + (size_t)(n * N_CHUNK + c) * KV_ELEMS);
    float4 s0 = pkv[0*256 + tid];
    float4 s1 = pkv[1*256 + tid];
    float4 s2 = pkv[2*256 + tid];
    float4 s3 = pkv[3*256 + tid];
    float4 s4 = pkv[4*256 + tid];
    float4 s5 = pkv[5*256 + tid];
    float4 s6 = pkv[6*256 + tid];
    float4 s7 = pkv[7*256 + tid];
    float kc = 0.f;
    if (tid < D2) kc = sumk[(n * N_CHUNK + c) * D2 + tid];

    __syncthreads();

    // Denominator: per-column running k-cumsum * q, once per block.
    if (tid < D2) {
        int pc = pad_col(tid);
#pragma unroll
        for (int l = 0; l < T_CHUNK; ++l) {
            kc += k_s[l][pc];
            part_s[l][tid] = q_s[l][pc] * kc;
        }
    }
    __syncthreads();

    {
        int l = tid >> 3, j = tid & 7;
        const float4* p4 = (const float4*)&part_s[l][j * 16];
        float4 aa = p4[0], bb = p4[1], cc = p4[2], dd = p4[3];
        float sum = ((aa.x + aa.y) + (aa.z + aa.w)) + ((bb.x + bb.y) + (bb.z + bb.w))
                  + ((cc.x + cc.y) + (cc.z + cc.w)) + ((dd.x + dd.y) + (dd.z + dd.w));
        sum = red8_dpp(sum);
        if (j == 0) rden_s[l] = 1.f / fmaxf(sum, 1e-6f);
    }
    __syncthreads();

    const int g = tid & 7, mh = (tid >> 3) << 1;
    const int gbase = pad_col(16 * g);

    float st0[16], st1[16];
    st0[0]=s0.x;  st0[1]=s0.y;  st0[2]=s0.z;  st0[3]=s0.w;
    st1[0]=s1.x;  st1[1]=s1.y;  st1[2]=s1.z;  st1[3]=s1.w;
    st0[4]=s2.x;  st0[5]=s2.y;  st0[6]=s2.z;  st0[7]=s2.w;
    st1[4]=s3.x;  st1[5]=s3.y;  st1[6]=s3.z;  st1[7]=s3.w;
    st0[8]=s4.x;  st0[9]=s4.y;  st0[10]=s4.z; st0[11]=s4.w;
    st1[8]=s5.x;  st1[9]=s5.y;  st1[10]=s5.z; st1[11]=s5.w;
    st0[12]=s6.x; st0[13]=s6.y; st0[14]=s6.z; st0[15]=s6.w;
    st1[12]=s7.x; st1[13]=s7.y; st1[14]=s7.z; st1[15]=s7.w;

    for (int l = 0; l < T_CHUNK; ++l) {
        float2 vm = *(const float2*)&v_s[l][mh];
        const float4* kv4 = (const float4*)&k_s[l][gbase];
        const float4* qv4 = (const float4*)&q_s[l][gbase];
        float a0 = 0.f, a1 = 0.f;
#pragma unroll
        for (int jj = 0; jj < 4; ++jj) {
            float4 kk = kv4[jj];
            float4 qq = qv4[jj];
            st0[4*jj+0] = fmaf(kk.x, vm.x, st0[4*jj+0]); a0 = fmaf(qq.x, st0[4*jj+0], a0);
            st1[4*jj+0] = fmaf(kk.x, vm.y, st1[4*jj+0]); a1 = fmaf(qq.x, st1[4*jj+0], a1);
            st0[4*jj+1] = fmaf(kk.y, vm.x, st0[4*jj+1]); a0 = fmaf(qq.y, st0[4*jj+1], a0);
            st1[4*jj+1] = fmaf(kk.y, vm.y, st1[4*jj+1]); a1 = fmaf(qq.y, st1[4*jj+1], a1);
            st0[4*jj+2] = fmaf(kk.z, vm.x, st0[4*jj+2]); a0 = fmaf(qq.z, st0[4*jj+2], a0);
            st1[4*jj+2] = fmaf(kk.z, vm.y, st1[4*jj+2]); a1 = fmaf(qq.z, st1[4*jj+2], a1);
            st0[4*jj+3] = fmaf(kk.w, vm.x, st0[4*jj+3]); a0 = fmaf(qq.w, st0[4*jj+3], a0);
            st1[4*jj+3] = fmaf(kk.w, vm.y, st1[4*jj+3]); a1 = fmaf(qq.w, st1[4*jj+3], a1);
        }
        a0 = red8_dpp(a0);
        a1 = red8_dpp(a1);
        if (g == 0) {
            float r = rden_s[l];
            *(float2*)&out_s[l][mh] = make_float2(a0 * r, a1 * r);
        }
    }
    __syncthreads();

    // Coalesced output store.
    {
        float4* o4 = (float4*)(out + base);
        const float4* s4o = (const float4*)&out_s[0][0];
        o4[tid] = s4o[tid];
        o4[256 + tid] = s4o[256 + tid];
    }
}

// ---------------------------------------------------------------------------
extern "C" void kernel_launch(void* const* d_in, const int* in_sizes, int n_in,
                              void* d_out, int out_size, void* d_ws, size_t ws_size,
                              hipStream_t stream) {
    (void)in_sizes; (void)n_in; (void)out_size; (void)ws_size;
    const float* q = (const float*)d_in[0];
    const float* k = (const float*)d_in[1];
    const float* v = (const float*)d_in[2];
    float* out = (float*)d_out;

    float* sumkv = (float*)d_ws;                                   // [N][C][8192] flat
    float* sumk  = sumkv + (size_t)N_HEADS * N_CHUNK * KV_ELEMS;   // [N][C][128]

    dim3 grid(N_CHUNK, N_HEADS);
    k1_chunk_sums<<<grid, 256, 0, stream>>>(k, v, sumkv, sumk);
    dim3 grid2(33, N_HEADS);
    k2_prefix<<<grid2, 256, 0, stream>>>(sumkv, sumk);
    k3_output<<<grid, 256, 0, stream>>>(q, k, v, sumkv, sumk, out);
}